// Round 6
// baseline (1274.048 us; speedup 1.0000x reference)
//
#include <hip/hip_runtime.h>
#include <hip/hip_bf16.h>
#include <stdint.h>
#include <stddef.h>

typedef short v8s __attribute__((ext_vector_type(8)));
typedef short v4s __attribute__((ext_vector_type(4)));
typedef float v4f __attribute__((ext_vector_type(4)));

#define STEPSZ 0.01f
#define MFMA(a, b, c) __builtin_amdgcn_mfma_f32_16x16x32_bf16((a), (b), (c), 0, 0, 0)

/* workspace layout (bytes) — all PLAIN row-major layouts */
#define OFF_ARE 0u        /* bf16 [2048][512] 2 MB : AreT rows (m*8+j) over n */
#define OFF_ATT 2097152u  /* bf16 [4096][256] 2 MB : AtT rows (n*8+j) over m (rev folded) */
#define OFF_XB  4194304u  /* bf16 [512][512] 512 KB : x operand rows (b*8+i) */
#define OFF_ERR 4718592u  /* bf16 [512][256] 256 KB : err operand rows (b*8+i) */
#define OFF_YT  4980736u  /* f32  [512][256] 512 KB : y transposed rows (b*8+k) */
#define OFF_BAR 5505024u  /* int [8][4][32] : per-cluster fe[2][32] then fx[2][32] */

/* ---- agent-scope (L3 coherence point) data path: no fences, no wbl2 ---- */
__device__ __forceinline__ v8s aload16(const void* p) {
  typedef unsigned long long u64;
  u64 lo = __hip_atomic_load((const u64*)p, __ATOMIC_RELAXED, __HIP_MEMORY_SCOPE_AGENT);
  u64 hi = __hip_atomic_load((const u64*)p + 1, __ATOMIC_RELAXED, __HIP_MEMORY_SCOPE_AGENT);
  union { u64 u; v4s s; } a, b;
  a.u = lo; b.u = hi;
  return __builtin_shufflevector(a.s, b.s, 0, 1, 2, 3, 4, 5, 6, 7);
}
__device__ __forceinline__ void astore_bf16(__hip_bfloat16* p, float v) {
  __hip_bfloat16 h = __float2bfloat16(v);
  unsigned short bits;
  __builtin_memcpy(&bits, &h, 2);
  __hip_atomic_store((unsigned short*)p, bits, __ATOMIC_RELAXED, __HIP_MEMORY_SCOPE_AGENT);
}

__global__ void prep_fwd(const float* __restrict__ A, __hip_bfloat16* __restrict__ AreT) {
  const int m = blockIdx.x;   // 256
  const int n = threadIdx.x;  // 512
  const float* ap = A + ((size_t)m * 512 + n) * 8;
#pragma unroll
  for (int j = 0; j < 8; ++j)
    AreT[(size_t)(m * 8 + j) * 512 + n] = __float2bfloat16(ap[j]);
}

__global__ void prep_bwd(const float* __restrict__ A, __hip_bfloat16* __restrict__ AtT) {
  const int n = blockIdx.x;   // 512
  const int m = threadIdx.x;  // 256
  const float* ap = A + ((size_t)m * 512 + n) * 8;
  const float rev[8] = {1.f, 1.f, 1.f, -1.f, 1.f, -1.f, -1.f, -1.f};
#pragma unroll
  for (int j = 0; j < 8; ++j)
    AtT[(size_t)(n * 8 + j) * 256 + m] = __float2bfloat16(ap[j] * rev[j]);
}

__global__ void prep_y(const float* __restrict__ y, float* __restrict__ yT) {
  const int r = blockIdx.x;   // 512
  const int m = threadIdx.x;  // 256
  yT[(size_t)r * 256 + m] = y[((size_t)(r >> 3) * 256 + m) * 8 + (r & 7)];
}

__global__ void zero_flags(int* __restrict__ bar) {
  __hip_atomic_store(bar + threadIdx.x, 0, __ATOMIC_RELAXED, __HIP_MEMORY_SCOPE_AGENT);
}

/* Persistent kernel: 256 blocks x 512 thr, 1 block/CU (145 KB LDS).
 * Cluster = blockIdx&7 (32 members, w = blockIdx>>3); owns batches
 * [cl*8,cl*8+8) = 64 GEMM rows, split into 2 sub-groups of 32 rows that are
 * software-pipelined so every flag wait has a compute stage of slack.
 * Block w owns fwd cols m in [w*8,w*8+8), bwd cols n in [w*16,w*16+16).
 * B operands persist in LDS all 50 iterations; cross-block data via
 * agent-scope atomics (L3) -> correct under any block->XCD mapping. */
__global__ __launch_bounds__(512, 2) void ista_persist(
    const __hip_bfloat16* __restrict__ AreT, const __hip_bfloat16* __restrict__ AtT,
    const float* __restrict__ yT, __hip_bfloat16* __restrict__ errb,
    __hip_bfloat16* __restrict__ xb, float* __restrict__ out, int* __restrict__ bars) {
  /* [0,64K) B1[64][512] | [64K,128K) B2[128][256] | [128K,+16896) Pt f32 (pitch 66 / 132)
   * B LDS: 16B chunk c of row r stored at chunk (c ^ (r&7)) */
  __shared__ __align__(16) char lds[147968];
  float* const Pt = (float*)(lds + 131072);

  const int tid = threadIdx.x;
  const int wave = tid >> 6, lane = tid & 63;
  const int fr = lane & 15, fq = lane >> 4;
  const int band = wave >> 2, cge = wave & 3;  // 2 row-bands x 4 col-groups
  const int cl = blockIdx.x & 7, w = blockIdx.x >> 3;
  const int rowbase = cl * 64;
  int* const fe = bars + cl * 128;       // fe[g*32 + slot]
  int* const fx = bars + cl * 128 + 64;  // fx[g*32 + slot]

  /* ---- prologue: load this block's B slices into persistent LDS (once) ---- */
  {
    const __hip_bfloat16* gB1 = AreT + (size_t)(w * 64) * 512;
    const __hip_bfloat16* gB2 = AtT + (size_t)(w * 128) * 256;
#pragma unroll
    for (int rr = 0; rr < 8; ++rr) {
      const int r = tid >> 3, c = (tid & 7) + rr * 8;          // 64 rows x 64 chunks
      v8s v = *(const v8s*)(gB1 + (size_t)r * 512 + c * 8);
      *(v8s*)(lds + r * 1024 + ((c ^ (r & 7)) << 4)) = v;
    }
#pragma unroll
    for (int rr = 0; rr < 8; ++rr) {
      const int r = tid >> 2, c = (tid & 3) + rr * 4;          // 128 rows x 32 chunks
      v8s v = *(const v8s*)(gB2 + (size_t)r * 256 + c * 8);
      *(v8s*)(lds + 65536 + r * 512 + ((c ^ (r & 7)) << 4)) = v;
    }
    __syncthreads();
  }

  /* wait for all 32 cluster slots (skip own: we know we arrived) */
  auto waitflags = [&](const int* f, int epv) {
    const int s = lane & 31;
    while (__any(s != w &&
                 __hip_atomic_load(f + s, __ATOMIC_RELAXED, __HIP_MEMORY_SCOPE_AGENT) < epv))
      __builtin_amdgcn_s_sleep(1);
    asm volatile("" ::: "memory");
  };

  float xreg[2] = {0.f, 0.f};
  const int k2 = (tid >> 4) & 7;  // P2 epilogue blade
  const float thr2 = (k2 == 0) ? 0.f : ((k2 == 7) ? 0.002f : 0.001f);

  /* ---- P1(g): err = recomb(x @ B1^T) - y for rows [g*32, g*32+32) ---- */
  auto phase1 = [&](int g) {
    const __hip_bfloat16* aRow = xb + (size_t)(rowbase + g * 32 + band * 16 + fr) * 512;
    v8s a[16];
#pragma unroll
    for (int kq = 0; kq < 16; ++kq) a[kq] = aload16(aRow + kq * 32 + fq * 8);
    v4f acc = {};
    const int rB = cge * 16 + fr;
    const char* const bBase = lds + rB * 1024;
    const int rx = (rB & 7);
#pragma unroll
    for (int kq = 0; kq < 16; ++kq) {
      v8s b = *(const v8s*)(bBase + (((kq * 4 + fq) ^ rx) << 4));
      acc = MFMA(a[kq], b, acc);
    }
#pragma unroll
    for (int v = 0; v < 4; ++v)
      Pt[(band * 16 + fq * 4 + v) * 66 + cge * 16 + fr] = acc[v];
    __syncthreads();
    if (tid < 256) {
      const int ro = tid >> 3, ml = tid & 7;
      const int bl = ro >> 3, k = ro & 7;
      float s = 0.f;
#pragma unroll
      for (int j = 0; j < 8; ++j) {
        const int i = k ^ j;
        const int cnt = __popc((i >> 1) & j) + __popc((i >> 2) & j);
        const float p = Pt[(bl * 8 + i) * 66 + ml * 8 + j];
        s += (cnt & 1) ? -p : p;
      }
      const size_t eidx = (size_t)(rowbase + g * 32 + ro) * 256 + w * 8 + ml;
      astore_bf16(errb + eidx, s - yT[eidx]);
      (void)bl;
    }
  };

  /* ---- P2(g): grad = recomb(err @ B2^T); x update for rows [g*32, +32) ---- */
  auto phase2 = [&](int g, int it) {
    const __hip_bfloat16* eRow = errb + (size_t)(rowbase + g * 32 + band * 16 + fr) * 256;
    v8s a[8];
#pragma unroll
    for (int kq = 0; kq < 8; ++kq) a[kq] = aload16(eRow + kq * 32 + fq * 8);
    v4f acc[2] = {};
#pragma unroll
    for (int kq = 0; kq < 8; ++kq) {
      const int c = kq * 4 + fq;
#pragma unroll
      for (int ct = 0; ct < 2; ++ct) {
        const int rB = cge * 32 + ct * 16 + fr;
        v8s b = *(const v8s*)(lds + 65536 + rB * 512 + ((c ^ (rB & 7)) << 4));
        acc[ct] = MFMA(a[kq], b, acc[ct]);
      }
    }
#pragma unroll
    for (int ct = 0; ct < 2; ++ct)
#pragma unroll
      for (int v = 0; v < 4; ++v)
        Pt[(band * 16 + fq * 4 + v) * 132 + cge * 32 + ct * 16 + fr] = acc[ct][v];
    __syncthreads();
    {
      const int ro = tid >> 4, nl = tid & 15;
      const int bl = ro >> 3;
      float s = 0.f;
#pragma unroll
      for (int j = 0; j < 8; ++j) {
        const int i = k2 ^ j;
        const int cnt = __popc((i >> 1) & j) + __popc((i >> 2) & j);
        const float p = Pt[(bl * 8 + i) * 132 + nl * 8 + j];
        s += (cnt & 1) ? -p : p;
      }
      float xv = xreg[g] - STEPSZ * s;
      const float ax = fabsf(xv) - thr2;
      xv = (ax > 0.f) ? copysignf(ax, xv) : 0.f;
      xreg[g] = xv;
      const int n = w * 16 + nl;
      astore_bf16(xb + (size_t)(rowbase + g * 32 + ro) * 512 + n, xv);
      if (it == 49) out[((size_t)(cl * 8 + g * 4 + bl) * 512 + n) * 8 + k2] = xv;
    }
  };

  for (int it = 0; it < 50; ++it) {
    if (it == 0) {
      /* x0 = 0 -> err = -y (both groups) */
      const int g = tid >> 8, t = tid & 255;
      const int ro = t >> 3, ml = t & 7;
      const size_t eidx = (size_t)(rowbase + g * 32 + ro) * 256 + w * 8 + ml;
      astore_bf16(errb + eidx, -yT[eidx]);
      __syncthreads();
      if (tid == 0) {
        __hip_atomic_store(fe + w, 1, __ATOMIC_RELAXED, __HIP_MEMORY_SCOPE_AGENT);
        __hip_atomic_store(fe + 32 + w, 1, __ATOMIC_RELAXED, __HIP_MEMORY_SCOPE_AGENT);
      }
    } else {
      waitflags(fx, it);
      phase1(0);
      __syncthreads();
      if (tid == 0)
        __hip_atomic_store(fe + w, it + 1, __ATOMIC_RELAXED, __HIP_MEMORY_SCOPE_AGENT);
      waitflags(fx + 32, it);
      phase1(1);
      __syncthreads();
      if (tid == 0)
        __hip_atomic_store(fe + 32 + w, it + 1, __ATOMIC_RELAXED, __HIP_MEMORY_SCOPE_AGENT);
    }
    waitflags(fe, it + 1);
    phase2(0, it);
    __syncthreads();
    if (tid == 0)
      __hip_atomic_store(fx + w, it + 1, __ATOMIC_RELAXED, __HIP_MEMORY_SCOPE_AGENT);
    waitflags(fe + 32, it + 1);
    phase2(1, it);
    if (it < 49) {
      __syncthreads();
      if (tid == 0)
        __hip_atomic_store(fx + 32 + w, it + 1, __ATOMIC_RELAXED, __HIP_MEMORY_SCOPE_AGENT);
    }
  }
}

extern "C" void kernel_launch(void* const* d_in, const int* in_sizes, int n_in,
                              void* d_out, int out_size, void* d_ws, size_t ws_size,
                              hipStream_t stream) {
  (void)in_sizes; (void)n_in; (void)out_size; (void)ws_size;
  const float* y = (const float*)d_in[0];
  const float* A = (const float*)d_in[1];
  float* out = (float*)d_out;
  char* ws = (char*)d_ws;

  __hip_bfloat16* AreT = (__hip_bfloat16*)(ws + OFF_ARE);
  __hip_bfloat16* AtT = (__hip_bfloat16*)(ws + OFF_ATT);
  __hip_bfloat16* xb = (__hip_bfloat16*)(ws + OFF_XB);
  __hip_bfloat16* errb = (__hip_bfloat16*)(ws + OFF_ERR);
  float* yT = (float*)(ws + OFF_YT);
  int* bars = (int*)(ws + OFF_BAR);

  prep_fwd<<<256, 512, 0, stream>>>(A, AreT);
  prep_bwd<<<512, 256, 0, stream>>>(A, AtT);
  prep_y<<<512, 256, 0, stream>>>(y, yT);
  zero_flags<<<1, 1024, 0, stream>>>(bars);

  ista_persist<<<256, 512, 0, stream>>>(AreT, AtT, yT, errb, xb, out, bars);
}

// Round 7
// 591.122 us; speedup vs baseline: 2.1553x; 2.1553x over previous
//
#include <hip/hip_runtime.h>
#include <hip/hip_bf16.h>
#include <stdint.h>
#include <stddef.h>

typedef short v8s __attribute__((ext_vector_type(8)));
typedef short v4s __attribute__((ext_vector_type(4)));
typedef float v4f __attribute__((ext_vector_type(4)));
typedef unsigned long long u64;

#define STEPSZ 0.01f
#define MFMA(a, b, c) __builtin_amdgcn_mfma_f32_16x16x32_bf16((a), (b), (c), 0, 0, 0)

/* workspace layout (bytes) */
#define OFF_ATT 0u        /* bf16 [4096][256] 2 MB : AtT rows (n*8+j)=A[m,n,j]*rev[j] over m */
#define OFF_GRT 2097152u  /* bf16 [4096][512] 4 MB : GramT rows (n*8+g) over n' */
#define OFF_CT  6291456u  /* f32  [512][512]  1 MB : cT rows (b*8+k) over n  (c = y*revA) */
#define OFF_YB  7340032u  /* bf16 [512][256] 256 KB: y blades rows (b*8+i) over m */
#define OFF_XB0 7602176u  /* bf16 [512][512] 512 KB: x operand buffer 0 */
#define OFF_XB1 8126464u  /* bf16 [512][512] 512 KB: x operand buffer 1 */
#define OFF_BAR 8650752u  /* int  [256]             : per-block flag slots */

__device__ __forceinline__ int csign(int i, int j) {  /* reorder parity of e_i * e_j */
  return (__popc((i >> 1) & j) + __popc((i >> 2) & j)) & 1;
}

/* ---- agent-scope (L3 coherence point) data path: no fences, no wbl2 ---- */
__device__ __forceinline__ v8s aload16(const void* p) {
  u64 lo = __hip_atomic_load((const u64*)p, __ATOMIC_RELAXED, __HIP_MEMORY_SCOPE_AGENT);
  u64 hi = __hip_atomic_load((const u64*)p + 1, __ATOMIC_RELAXED, __HIP_MEMORY_SCOPE_AGENT);
  union { u64 u; v4s s; } a, b;
  a.u = lo; b.u = hi;
  return __builtin_shufflevector(a.s, b.s, 0, 1, 2, 3, 4, 5, 6, 7);
}
__device__ __forceinline__ void astore8(void* p, u64 v) {
  __hip_atomic_store((u64*)p, v, __ATOMIC_RELAXED, __HIP_MEMORY_SCOPE_AGENT);
}

__global__ void prep_at(const float* __restrict__ A, __hip_bfloat16* __restrict__ AtT) {
  const int n = blockIdx.x;   // 512
  const int m = threadIdx.x;  // 256
  const float* ap = A + ((size_t)m * 512 + n) * 8;
  const float rev[8] = {1.f, 1.f, 1.f, -1.f, 1.f, -1.f, -1.f, -1.f};
#pragma unroll
  for (int j = 0; j < 8; ++j)
    AtT[(size_t)(n * 8 + j) * 256 + m] = __float2bfloat16(ap[j] * rev[j]);
}

__global__ void prep_yb(const float* __restrict__ y, __hip_bfloat16* __restrict__ yb) {
  const int r = blockIdx.x;   // 512 = b*8+i
  const int m = threadIdx.x;  // 256
  yb[(size_t)r * 256 + m] = __float2bfloat16(y[((size_t)(r >> 3) * 256 + m) * 8 + (r & 7)]);
}

__global__ void zero_flags(int* __restrict__ bar) {
  __hip_atomic_store(bar + threadIdx.x, 0, __ATOMIC_RELAXED, __HIP_MEMORY_SCOPE_AGENT);
}

/* c[b,n,k] = (y * rev(A))[k] : identical structure to the verified P2 phase.
 * grid (64, 8): cols = AtT rows (n,j), rows = yb rows (b,i), K = 256. */
__global__ __launch_bounds__(256) void c_kernel(const __hip_bfloat16* __restrict__ yb,
                                                const __hip_bfloat16* __restrict__ AtT,
                                                float* __restrict__ cT) {
  __shared__ float Pt[64 * 66];
  const int tid = threadIdx.x;
  const int wave = tid >> 6, lane = tid & 63;
  const int fr = lane & 15, fq = lane >> 4;
  const int wr = (wave >> 1) * 32, wc = (wave & 1) * 32;
  const int r0 = blockIdx.y * 64, c0 = blockIdx.x * 64;
  v4f acc[2][2] = {};
  for (int k0 = 0; k0 < 256; k0 += 32) {
    v8s a0 = *(const v8s*)(yb + (size_t)(r0 + wr + fr) * 256 + k0 + fq * 8);
    v8s a1 = *(const v8s*)(yb + (size_t)(r0 + wr + 16 + fr) * 256 + k0 + fq * 8);
    v8s b0 = *(const v8s*)(AtT + (size_t)(c0 + wc + fr) * 256 + k0 + fq * 8);
    v8s b1 = *(const v8s*)(AtT + (size_t)(c0 + wc + 16 + fr) * 256 + k0 + fq * 8);
    acc[0][0] = MFMA(a0, b0, acc[0][0]);
    acc[0][1] = MFMA(a0, b1, acc[0][1]);
    acc[1][0] = MFMA(a1, b0, acc[1][0]);
    acc[1][1] = MFMA(a1, b1, acc[1][1]);
  }
#pragma unroll
  for (int r = 0; r < 2; ++r)
#pragma unroll
    for (int c = 0; c < 2; ++c)
#pragma unroll
      for (int v = 0; v < 4; ++v)
        Pt[(wr + r * 16 + fq * 4 + v) * 66 + wc + c * 16 + fr] = acc[r][c][v];
  __syncthreads();
  for (int o = tid; o < 512; o += 256) {
    const int bl = o >> 6, k = (o >> 3) & 7, nl = o & 7;
    float s = 0.f;
#pragma unroll
    for (int j = 0; j < 8; ++j) {
      const int i = k ^ j;
      const float p = Pt[(bl * 8 + i) * 66 + nl * 8 + j];
      s += csign(i, j) ? -p : p;
    }
    cT[((size_t)((blockIdx.y * 8 + bl) * 8 + k)) * 512 + blockIdx.x * 8 + nl] = s;
  }
}

/* GramT[(n*8+g)][n'] = (A[:,n'] * rev(A[:,n]))[g] via S = AtT@AtT^T and
 * sign fold: P_g = rev(j')*S  =>  extra rev[i] (i=g^j) in the recombine. */
__global__ __launch_bounds__(256) void gram_kernel(const __hip_bfloat16* __restrict__ AtT,
                                                   __hip_bfloat16* __restrict__ GrT) {
  __shared__ float Pt[64 * 66];
  const int tid = threadIdx.x;
  const int wave = tid >> 6, lane = tid & 63;
  const int fr = lane & 15, fq = lane >> 4;
  const int wr = (wave >> 1) * 32, wc = (wave & 1) * 32;
  const int r0 = blockIdx.y * 64, c0 = blockIdx.x * 64;  // rows=(n',j'), cols=(n,j)
  v4f acc[2][2] = {};
  for (int k0 = 0; k0 < 256; k0 += 32) {
    v8s a0 = *(const v8s*)(AtT + (size_t)(r0 + wr + fr) * 256 + k0 + fq * 8);
    v8s a1 = *(const v8s*)(AtT + (size_t)(r0 + wr + 16 + fr) * 256 + k0 + fq * 8);
    v8s b0 = *(const v8s*)(AtT + (size_t)(c0 + wc + fr) * 256 + k0 + fq * 8);
    v8s b1 = *(const v8s*)(AtT + (size_t)(c0 + wc + 16 + fr) * 256 + k0 + fq * 8);
    acc[0][0] = MFMA(a0, b0, acc[0][0]);
    acc[0][1] = MFMA(a0, b1, acc[0][1]);
    acc[1][0] = MFMA(a1, b0, acc[1][0]);
    acc[1][1] = MFMA(a1, b1, acc[1][1]);
  }
#pragma unroll
  for (int r = 0; r < 2; ++r)
#pragma unroll
    for (int c = 0; c < 2; ++c)
#pragma unroll
      for (int v = 0; v < 4; ++v)
        Pt[(wr + r * 16 + fq * 4 + v) * 66 + wc + c * 16 + fr] = acc[r][c][v];
  __syncthreads();
  const float rev[8] = {1.f, 1.f, 1.f, -1.f, 1.f, -1.f, -1.f, -1.f};
  for (int o = tid; o < 512; o += 256) {
    const int nl = o >> 6, g = (o >> 3) & 7, npl = o & 7;
    float s = 0.f;
#pragma unroll
    for (int j = 0; j < 8; ++j) {
      const int i = g ^ j;  /* = j' */
      const float sg = (csign(i, j) ? -1.f : 1.f) * rev[i];
      s += sg * Pt[(npl * 8 + i) * 66 + nl * 8 + j];
    }
    GrT[((size_t)((blockIdx.x * 8 + nl) * 8 + g)) * 512 + blockIdx.y * 8 + npl] =
        __float2bfloat16(s);
  }
}

/* Persistent kernel: 256 blocks x 512 thr, 1 block/CU (~147 KB LDS).
 * Cluster = blockIdx&7 (32 members, w = blockIdx>>3); owns batches
 * [cl*8,cl*8+8) = 64 rows (b,i). Block w owns n in [w*16,+16) = 128 Gram rows,
 * LDS-resident all 50 iters. ONE GEMM phase + ONE barrier per iteration:
 * x_{t+1} = shrink(x_t - eta*(recomb(x_t @ GramT^T) - c)). x double-buffered
 * (flag protocol bounds drift to 1 iter). */
__global__ __launch_bounds__(512, 2) void ista_persist(
    const __hip_bfloat16* __restrict__ GrT, const float* __restrict__ cT,
    __hip_bfloat16* __restrict__ xb0, __hip_bfloat16* __restrict__ xb1,
    float* __restrict__ out, int* __restrict__ bars) {
  /* [0,128K) Gram slice [128][512] bf16 (chunk c at c^(r&7)) |
   * [128K,+16896) Pt f32[64][66] | then stage bf16[64][16] (2 KB) */
  __shared__ __align__(16) char lds[150016];
  float* const Pt = (float*)(lds + 131072);
  __hip_bfloat16* const stage = (__hip_bfloat16*)(lds + 131072 + 16896);

  const int tid = threadIdx.x;
  const int wave = tid >> 6, lane = tid & 63;
  const int fr = lane & 15, fq = lane >> 4;
  const int band = wave >> 1, cg = wave & 1;  // 4 row-bands x 2 col-halves
  const int cl = blockIdx.x & 7, w = blockIdx.x >> 3;
  const int rowbase = cl * 64;
  int* const flags = bars + cl * 32;

  /* prologue: Gram rows [w*128,+128) -> LDS (plain cached loads, one-time) */
  {
    const __hip_bfloat16* g = GrT + (size_t)(w * 128) * 512;
    const int r = tid >> 2;
#pragma unroll
    for (int rr = 0; rr < 16; ++rr) {
      const int c = (tid & 3) + rr * 4;
      v8s v = *(const v8s*)(g + (size_t)r * 512 + c * 8);
      *(v8s*)(lds + r * 1024 + ((c ^ (r & 7)) << 4)) = v;
    }
    __syncthreads();
  }

  float xreg[2] = {0.f, 0.f};
  const int ro = tid >> 3, nl = tid & 7;  // epilogue output (row, n-local)
  const int bl = ro >> 3, k = ro & 7;
  const float thr = (k == 0) ? 0.f : ((k == 7) ? 0.002f : 0.001f);
  const float* const crow = cT + (size_t)((cl * 8 + bl) * 8 + k) * 512 + w * 16 + nl;
  float* const orow = out + ((size_t)(cl * 8 + bl) * 512 + w * 16 + nl) * 8 + k;

  for (int it = 0; it < 50; ++it) {
    /* wait: all cluster members finished iter it-1 (skip own slot) */
    if (tid < 64) {
      const int s = tid & 31;
      if (s != w)
        while (__hip_atomic_load(flags + s, __ATOMIC_RELAXED, __HIP_MEMORY_SCOPE_AGENT) < it)
          __builtin_amdgcn_s_sleep(1);
    }
    asm volatile("" ::: "memory");
    __syncthreads();

    v4f acc[4] = {};
    if (it > 0) {
      const __hip_bfloat16* xr = (it & 1) ? xb1 : xb0;
      const __hip_bfloat16* aRow = xr + (size_t)(rowbase + band * 16 + fr) * 512;
      v8s a[16];
#pragma unroll
      for (int kq = 0; kq < 16; ++kq) a[kq] = aload16(aRow + kq * 32 + fq * 8);
#pragma unroll
      for (int kq = 0; kq < 16; ++kq) {
        const int c = kq * 4 + fq;
#pragma unroll
        for (int ct = 0; ct < 4; ++ct) {
          const int rB = cg * 64 + ct * 16 + fr;
          v8s b = *(const v8s*)(lds + rB * 1024 + ((c ^ (rB & 7)) << 4));
          acc[ct] = MFMA(a[kq], b, acc[ct]);
        }
      }
    }
    /* epilogue: two column-halves (h = Gram col-half = n in [w*16+h*8,+8)) */
    __hip_bfloat16* const xw = (it & 1) ? xb0 : xb1;
#pragma unroll
    for (int h = 0; h < 2; ++h) {
      if (it > 0) {
        if (h == 1) __syncthreads();
        if (cg == h) {
#pragma unroll
          for (int ct = 0; ct < 4; ++ct)
#pragma unroll
            for (int v = 0; v < 4; ++v)
              Pt[(band * 16 + fq * 4 + v) * 66 + ct * 16 + fr] = acc[ct][v];
        }
        __syncthreads();
      }
      float s = 0.f;
      if (it > 0) {
#pragma unroll
        for (int j = 0; j < 8; ++j) {
          const int i = k ^ j;
          const float p = Pt[(bl * 8 + i) * 66 + nl * 8 + j];
          s += csign(i, j) ? -p : p;
        }
      }
      float xv = xreg[h] - STEPSZ * (s - crow[h * 8]);
      const float ax = fabsf(xv) - thr;
      xv = (ax > 0.f) ? copysignf(ax, xv) : 0.f;
      xreg[h] = xv;
      stage[ro * 16 + h * 8 + nl] = __float2bfloat16(xv);
      if (it == 49) orow[h * 64] = xv;  /* out stride: 8 n-steps * 8 blades */
    }
    __syncthreads();  /* stage complete */
    if (tid < 256) {
      const int row = tid >> 2, part = tid & 3;
      u64 v = *(const u64*)(stage + row * 16 + part * 4);
      astore8(xw + (size_t)(rowbase + row) * 512 + w * 16 + part * 4, v);
    }
    __syncthreads();  /* drains the agent stores (vmcnt) in every wave */
    if (tid == 0)
      __hip_atomic_store(flags + w, it + 1, __ATOMIC_RELAXED, __HIP_MEMORY_SCOPE_AGENT);
  }
}

extern "C" void kernel_launch(void* const* d_in, const int* in_sizes, int n_in,
                              void* d_out, int out_size, void* d_ws, size_t ws_size,
                              hipStream_t stream) {
  (void)in_sizes; (void)n_in; (void)out_size; (void)ws_size;
  const float* y = (const float*)d_in[0];
  const float* A = (const float*)d_in[1];
  float* out = (float*)d_out;
  char* ws = (char*)d_ws;

  __hip_bfloat16* AtT = (__hip_bfloat16*)(ws + OFF_ATT);
  __hip_bfloat16* GrT = (__hip_bfloat16*)(ws + OFF_GRT);
  float* cT = (float*)(ws + OFF_CT);
  __hip_bfloat16* yb = (__hip_bfloat16*)(ws + OFF_YB);
  __hip_bfloat16* xb0 = (__hip_bfloat16*)(ws + OFF_XB0);
  __hip_bfloat16* xb1 = (__hip_bfloat16*)(ws + OFF_XB1);
  int* bars = (int*)(ws + OFF_BAR);

  prep_at<<<512, 256, 0, stream>>>(A, AtT);
  prep_yb<<<512, 256, 0, stream>>>(y, yb);
  c_kernel<<<dim3(64, 8), 256, 0, stream>>>(yb, AtT, cT);
  gram_kernel<<<dim3(64, 64), 256, 0, stream>>>(AtT, GrT);
  zero_flags<<<1, 256, 0, stream>>>(bars);

  ista_persist<<<256, 512, 0, stream>>>(GrT, cT, xb0, xb1, out, bars);
}

// Round 8
// 373.620 us; speedup vs baseline: 3.4100x; 1.5821x over previous
//
#include <hip/hip_runtime.h>
#include <hip/hip_bf16.h>
#include <stdint.h>
#include <stddef.h>

typedef short v8s __attribute__((ext_vector_type(8)));
typedef short v4s __attribute__((ext_vector_type(4)));
typedef float v4f __attribute__((ext_vector_type(4)));
typedef float v16f __attribute__((ext_vector_type(16)));
typedef unsigned long long u64;

#define STEPSZ 0.01f
#define MFMA16(a, b, c) __builtin_amdgcn_mfma_f32_16x16x32_bf16((a), (b), (c), 0, 0, 0)
#define MFMA32(a, b, c) __builtin_amdgcn_mfma_f32_32x32x16_bf16((a), (b), (c), 0, 0, 0)

/* workspace layout (bytes) */
#define OFF_ATT 0u        /* bf16 [4096][256] 2 MB : AtT rows (n*8+j)=A[m,n,j]*rev[j] over m */
#define OFF_GRT 2097152u  /* bf16 [4096][512] 4 MB : GramT rows (n*8+g) over n' */
#define OFF_CT  6291456u  /* f32  [512][512]  1 MB : cT rows (b*8+k) over n */
#define OFF_YB  7340032u  /* bf16 [512][256] 256 KB: y blades rows (b*8+i) over m */
#define OFF_XB0 7602176u  /* bf16 [512][512] 512 KB: x operand buffer 0 */
#define OFF_XB1 8126464u  /* bf16 [512][512] 512 KB: x operand buffer 1 */
#define OFF_BAR 8650752u  /* int  [256]             : per-block flag slots */

__device__ __forceinline__ int csign(int i, int j) {  /* reorder parity of e_i * e_j */
  return (__popc((i >> 1) & j) + __popc((i >> 2) & j)) & 1;
}

/* ---- agent-scope (L3 coherence point) data path: no fences, no wbl2 ---- */
__device__ __forceinline__ v8s aload16(const void* p) {
  u64 lo = __hip_atomic_load((const u64*)p, __ATOMIC_RELAXED, __HIP_MEMORY_SCOPE_AGENT);
  u64 hi = __hip_atomic_load((const u64*)p + 1, __ATOMIC_RELAXED, __HIP_MEMORY_SCOPE_AGENT);
  union { u64 u; v4s s; } a, b;
  a.u = lo; b.u = hi;
  return __builtin_shufflevector(a.s, b.s, 0, 1, 2, 3, 4, 5, 6, 7);
}

__global__ void prep_at(const float* __restrict__ A, __hip_bfloat16* __restrict__ AtT) {
  const int n = blockIdx.x;   // 512
  const int m = threadIdx.x;  // 256
  const float* ap = A + ((size_t)m * 512 + n) * 8;
  const float rev[8] = {1.f, 1.f, 1.f, -1.f, 1.f, -1.f, -1.f, -1.f};
#pragma unroll
  for (int j = 0; j < 8; ++j)
    AtT[(size_t)(n * 8 + j) * 256 + m] = __float2bfloat16(ap[j] * rev[j]);
}

__global__ void prep_yb(const float* __restrict__ y, __hip_bfloat16* __restrict__ yb) {
  const int r = blockIdx.x;   // 512 = b*8+i
  const int m = threadIdx.x;  // 256
  yb[(size_t)r * 256 + m] = __float2bfloat16(y[((size_t)(r >> 3) * 256 + m) * 8 + (r & 7)]);
}

__global__ void zero_flags(int* __restrict__ bar) {
  __hip_atomic_store(bar + threadIdx.x, 0, __ATOMIC_RELAXED, __HIP_MEMORY_SCOPE_AGENT);
}

/* c[b,n,k] = (y * rev(A))[k]  (verified r7 structure) */
__global__ __launch_bounds__(256) void c_kernel(const __hip_bfloat16* __restrict__ yb,
                                                const __hip_bfloat16* __restrict__ AtT,
                                                float* __restrict__ cT) {
  __shared__ float Pt[64 * 66];
  const int tid = threadIdx.x;
  const int wave = tid >> 6, lane = tid & 63;
  const int fr = lane & 15, fq = lane >> 4;
  const int wr = (wave >> 1) * 32, wc = (wave & 1) * 32;
  const int r0 = blockIdx.y * 64, c0 = blockIdx.x * 64;
  v4f acc[2][2] = {};
  for (int k0 = 0; k0 < 256; k0 += 32) {
    v8s a0 = *(const v8s*)(yb + (size_t)(r0 + wr + fr) * 256 + k0 + fq * 8);
    v8s a1 = *(const v8s*)(yb + (size_t)(r0 + wr + 16 + fr) * 256 + k0 + fq * 8);
    v8s b0 = *(const v8s*)(AtT + (size_t)(c0 + wc + fr) * 256 + k0 + fq * 8);
    v8s b1 = *(const v8s*)(AtT + (size_t)(c0 + wc + 16 + fr) * 256 + k0 + fq * 8);
    acc[0][0] = MFMA16(a0, b0, acc[0][0]);
    acc[0][1] = MFMA16(a0, b1, acc[0][1]);
    acc[1][0] = MFMA16(a1, b0, acc[1][0]);
    acc[1][1] = MFMA16(a1, b1, acc[1][1]);
  }
#pragma unroll
  for (int r = 0; r < 2; ++r)
#pragma unroll
    for (int c = 0; c < 2; ++c)
#pragma unroll
      for (int v = 0; v < 4; ++v)
        Pt[(wr + r * 16 + fq * 4 + v) * 66 + wc + c * 16 + fr] = acc[r][c][v];
  __syncthreads();
  for (int o = tid; o < 512; o += 256) {
    const int bl = o >> 6, k = (o >> 3) & 7, nl = o & 7;
    float s = 0.f;
#pragma unroll
    for (int j = 0; j < 8; ++j) {
      const int i = k ^ j;
      const float p = Pt[(bl * 8 + i) * 66 + nl * 8 + j];
      s += csign(i, j) ? -p : p;
    }
    cT[((size_t)((blockIdx.y * 8 + bl) * 8 + k)) * 512 + blockIdx.x * 8 + nl] = s;
  }
}

/* GramT[(n*8+g)][n'] = (A[:,n'] * rev(A[:,n]))[g]  (verified r7 structure) */
__global__ __launch_bounds__(256) void gram_kernel(const __hip_bfloat16* __restrict__ AtT,
                                                   __hip_bfloat16* __restrict__ GrT) {
  __shared__ float Pt[64 * 66];
  const int tid = threadIdx.x;
  const int wave = tid >> 6, lane = tid & 63;
  const int fr = lane & 15, fq = lane >> 4;
  const int wr = (wave >> 1) * 32, wc = (wave & 1) * 32;
  const int r0 = blockIdx.y * 64, c0 = blockIdx.x * 64;
  v4f acc[2][2] = {};
  for (int k0 = 0; k0 < 256; k0 += 32) {
    v8s a0 = *(const v8s*)(AtT + (size_t)(r0 + wr + fr) * 256 + k0 + fq * 8);
    v8s a1 = *(const v8s*)(AtT + (size_t)(r0 + wr + 16 + fr) * 256 + k0 + fq * 8);
    v8s b0 = *(const v8s*)(AtT + (size_t)(c0 + wc + fr) * 256 + k0 + fq * 8);
    v8s b1 = *(const v8s*)(AtT + (size_t)(c0 + wc + 16 + fr) * 256 + k0 + fq * 8);
    acc[0][0] = MFMA16(a0, b0, acc[0][0]);
    acc[0][1] = MFMA16(a0, b1, acc[0][1]);
    acc[1][0] = MFMA16(a1, b0, acc[1][0]);
    acc[1][1] = MFMA16(a1, b1, acc[1][1]);
  }
#pragma unroll
  for (int r = 0; r < 2; ++r)
#pragma unroll
    for (int c = 0; c < 2; ++c)
#pragma unroll
      for (int v = 0; v < 4; ++v)
        Pt[(wr + r * 16 + fq * 4 + v) * 66 + wc + c * 16 + fr] = acc[r][c][v];
  __syncthreads();
  const float rev[8] = {1.f, 1.f, 1.f, -1.f, 1.f, -1.f, -1.f, -1.f};
  for (int o = tid; o < 512; o += 256) {
    const int nl = o >> 6, g = (o >> 3) & 7, npl = o & 7;
    float s = 0.f;
#pragma unroll
    for (int j = 0; j < 8; ++j) {
      const int i = g ^ j;
      const float sg = (csign(i, j) ? -1.f : 1.f) * rev[i];
      s += sg * Pt[(npl * 8 + i) * 66 + nl * 8 + j];
    }
    GrT[((size_t)((blockIdx.x * 8 + nl) * 8 + g)) * 512 + blockIdx.y * 8 + npl] =
        __float2bfloat16(s);
  }
}

/* Persistent kernel: 256 blocks x 512 thr, 1 block/CU.
 * Cluster = 16 blocks (2 clusters per XCD under %8): cl = (bid&7)*2 + (bid>>7),
 * w = (bid>>3)&15. Cluster owns 4 batches = 32 GEMM rows (b,i).
 * Block w owns n in [w*32,+32) -> 256 GramT rows held ENTIRELY IN VGPRS
 * (8 waves x 128 persistent VGPRs). mfma 32x32x16: M=32 (cluster rows),
 * per wave one 32-col N-tile, K=512. x staged in LDS (32 KB, XOR-16 swizzle).
 * One flag barrier + one 32 KB x-exchange per iteration. */
__global__ __launch_bounds__(512, 2) void ista_persist(
    const __hip_bfloat16* __restrict__ GrT, const float* __restrict__ cT,
    __hip_bfloat16* __restrict__ xb0, __hip_bfloat16* __restrict__ xb1,
    float* __restrict__ out, int* __restrict__ bars) {
  /* [0,32K) x-stage [32 rows][1024 B] (chunk c at slot c^(row&15)) |
   * [32K,+34304) Pt f32 [32][pitch 268] */
  __shared__ __align__(16) char lds[32768 + 34304];
  float* const Pt = (float*)(lds + 32768);

  const int tid = threadIdx.x;
  const int wave = tid >> 6, lane = tid & 63;
  const int lr = lane & 31, lh = lane >> 5;  // tile row/col, k-half
  const int cl = (blockIdx.x & 7) * 2 + (blockIdx.x >> 7);
  const int w = (blockIdx.x >> 3) & 15;
  const int rowbase = cl * 32;
  int* const flags = bars + cl * 16;

  /* persistent B in VGPRs: GramT rows [w*256 + wave*32 + lr], all K (plain
   * cached loads; GrT immutable and never invalidated - no fences anywhere) */
  v8s B[32];
  {
    const __hip_bfloat16* gB = GrT + (size_t)(w * 256 + wave * 32 + lr) * 512 + lh * 8;
#pragma unroll
    for (int kt = 0; kt < 32; ++kt) B[kt] = *(const v8s*)(gB + kt * 16);
  }

  /* x-stage addressing */
  const int srow = tid >> 4, scol = tid & 15;
  /* epilogue mapping: 512 threads x 2 outputs (n = en*2 + {0,1}) */
  const int eb = tid >> 7, ek = (tid >> 4) & 7, en = tid & 15;
  const int xrow = rowbase + eb * 8 + ek;  // next-iter A row (b,i=k)
  const float thr = (ek == 0) ? 0.f : ((ek == 7) ? 0.002f : 0.001f);
  const float* const crow = cT + (size_t)(xrow)*512 + w * 32 + en * 2;
  float* const orow = out + ((size_t)(cl * 4 + eb) * 512 + w * 32 + en * 2) * 8 + ek;
  float xreg[2] = {0.f, 0.f};

  for (int it = 0; it < 50; ++it) {
    if (it > 0) {
      /* wait: all cluster members posted iter it (skip own slot) */
      if (tid < 16 && tid != w)
        while (__hip_atomic_load(flags + tid, __ATOMIC_RELAXED, __HIP_MEMORY_SCOPE_AGENT) < it)
          __builtin_amdgcn_s_sleep(1);
      asm volatile("" ::: "memory");
      __syncthreads();
      /* stage x_(it) into LDS: 32 rows x 1 KB, agent loads (L3) */
      {
        const __hip_bfloat16* xr = (it & 1) ? xb1 : xb0;
        const __hip_bfloat16* g = xr + (size_t)(rowbase + srow) * 512;
#pragma unroll
        for (int rr = 0; rr < 4; ++rr) {
          const int c = scol + rr * 16;
          v8s v = aload16(g + c * 8);
          *(v8s*)(lds + srow * 1024 + ((c ^ (srow & 15)) << 4)) = v;
        }
      }
      __syncthreads();
      /* K-loop: 32 MFMAs, B from regs, A from LDS (2-way swizzle = free) */
      v16f acc = {};
#pragma unroll
      for (int kt = 0; kt < 32; ++kt) {
        const int cidx = kt * 2 + lh;
        v8s a = *(const v8s*)(lds + lr * 1024 + ((cidx ^ (lr & 15)) << 4));
        acc = MFMA32(a, B[kt], acc);
      }
      /* dump P tile: C/D layout col=lane&31, row=(r&3)+8*(r>>2)+4*(lane>>5) */
#pragma unroll
      for (int r = 0; r < 16; ++r)
        Pt[((r & 3) + 8 * (r >> 2) + 4 * lh) * 268 + wave * 32 + lr] = acc[r];
    }
    __syncthreads();
    /* epilogue: blade recombine + ISTA update + x publish */
    {
      __hip_bfloat16* const xw = (it & 1) ? xb0 : xb1;
      unsigned int pack = 0;
#pragma unroll
      for (int c = 0; c < 2; ++c) {
        const int n = en * 2 + c;
        float s = 0.f;
        if (it > 0) {
#pragma unroll
          for (int j = 0; j < 8; ++j) {
            const int i = ek ^ j;
            const float p = Pt[(eb * 8 + i) * 268 + n * 8 + j];
            s += csign(i, j) ? -p : p;
          }
        }
        float xv = xreg[c] - STEPSZ * (s - crow[c]);
        const float ax = fabsf(xv) - thr;
        xv = (ax > 0.f) ? copysignf(ax, xv) : 0.f;
        xreg[c] = xv;
        __hip_bfloat16 h = __float2bfloat16(xv);
        unsigned short bits;
        __builtin_memcpy(&bits, &h, 2);
        pack |= ((unsigned int)bits) << (c * 16);
        if (it == 49) orow[c * 8] = xv;
      }
      __hip_atomic_store((unsigned int*)(xw + (size_t)xrow * 512 + w * 32 + en * 2),
                         pack, __ATOMIC_RELAXED, __HIP_MEMORY_SCOPE_AGENT);
    }
    __syncthreads();  /* per-wave vmcnt(0) drain -> all stores at L3 */
    if (tid == 0)
      __hip_atomic_store(flags + w, it + 1, __ATOMIC_RELAXED, __HIP_MEMORY_SCOPE_AGENT);
  }
}

extern "C" void kernel_launch(void* const* d_in, const int* in_sizes, int n_in,
                              void* d_out, int out_size, void* d_ws, size_t ws_size,
                              hipStream_t stream) {
  (void)in_sizes; (void)n_in; (void)out_size; (void)ws_size;
  const float* y = (const float*)d_in[0];
  const float* A = (const float*)d_in[1];
  float* out = (float*)d_out;
  char* ws = (char*)d_ws;

  __hip_bfloat16* AtT = (__hip_bfloat16*)(ws + OFF_ATT);
  __hip_bfloat16* GrT = (__hip_bfloat16*)(ws + OFF_GRT);
  float* cT = (float*)(ws + OFF_CT);
  __hip_bfloat16* yb = (__hip_bfloat16*)(ws + OFF_YB);
  __hip_bfloat16* xb0 = (__hip_bfloat16*)(ws + OFF_XB0);
  __hip_bfloat16* xb1 = (__hip_bfloat16*)(ws + OFF_XB1);
  int* bars = (int*)(ws + OFF_BAR);

  prep_at<<<512, 256, 0, stream>>>(A, AtT);
  prep_yb<<<512, 256, 0, stream>>>(y, yb);
  c_kernel<<<dim3(64, 8), 256, 0, stream>>>(yb, AtT, cT);
  gram_kernel<<<dim3(64, 64), 256, 0, stream>>>(AtT, GrT);
  zero_flags<<<1, 256, 0, stream>>>(bars);

  ista_persist<<<256, 512, 0, stream>>>(GrT, cT, xb0, xb1, out, bars);
}